// Round 2
// baseline (647.833 us; speedup 1.0000x reference)
//
#include <hip/hip_runtime.h>
#include <stdint.h>

typedef unsigned short u16;
typedef __attribute__((ext_vector_type(8))) __bf16 bf16x8;
typedef __attribute__((ext_vector_type(4))) float f32x4;
typedef __attribute__((ext_vector_type(4))) u16 u16x4;
typedef __attribute__((ext_vector_type(8))) u16 u16x8;

#define BM 128
#define BN 128
#define BK 32
#define MTOT 4096

__device__ __forceinline__ u16 f2bf(float f) {
  union { float f; uint32_t u; } x; x.f = f;
  uint32_t r = x.u + 0x7FFFu + ((x.u >> 16) & 1u);
  return (u16)(r >> 16);
}

__device__ __forceinline__ void gload16(const void* g, void* lds) {
  __builtin_amdgcn_global_load_lds(
      (const __attribute__((address_space(1))) void*)g,
      (__attribute__((address_space(3))) void*)lds, 16, 0, 0);
}

struct ViewParams {
  const void* A;    // [M][lda] row-major; fp32 if AF32 else bf16
  const u16* BT;    // [N][K] row-major bf16 (B transposed)
  void* C;          // bf16 unless CF32
  const float* bias;
  int K, lda, N;
};
struct Params5 { ViewParams v[5]; };

// FLAGS: 1 = transposed bf16 store (C is [N][4096]), 2 = +bias, 4 = relu
template <int FLAGS, bool AF32, bool CF32>
__global__ __launch_bounds__(256) void gemm_kernel(Params5 p, int tilesPerView, int ntiles) {
  constexpr int ABYTES = AF32 ? (BM * BK * 4) : (BM * BK * 2);
  __shared__ __align__(16) char smem[ABYTES + BN * BK * 2];
  u16* Bs = (u16*)(smem + ABYTES);

  const int bid = blockIdx.x;
  const int view = bid / tilesPerView;
  const int t = bid - view * tilesPerView;
  const int nt = t % ntiles;
  const int mt = t / ntiles;
  ViewParams vp = p.v[view];
  const int K = vp.K, lda = vp.lda, N = vp.N;
  const int m0 = mt * BM, n0 = nt * BN;

  const int tid = threadIdx.x;
  const int wave = tid >> 6;
  const int lane = tid & 63;

  // ---- B staging (bf16): rows of 32 u16 = 64B = 4 chunks, XOR-4 swizzle
  const int srow = lane >> 2;
  const int slot4 = lane & 3;
  const int rB0 = wave * 32 + srow;
  const int rB1 = rB0 + 16;
  const int cB0 = slot4 ^ ((rB0 >> 1) & 3);
  const int cB1 = slot4 ^ ((rB1 >> 1) & 3);
  const u16* gB0 = vp.BT + (size_t)(n0 + rB0) * K + cB0 * 8;
  const u16* gB1 = vp.BT + (size_t)(n0 + rB1) * K + cB1 * 8;
  u16* lB0 = Bs + (wave * 32) * 32;
  u16* lB1 = Bs + (wave * 32 + 16) * 32;

  // ---- A staging
  const float* gAf[4];
  float* lAf[4];
  const u16 *gAb0 = nullptr, *gAb1 = nullptr;
  u16 *lAb0 = nullptr, *lAb1 = nullptr;
  if constexpr (AF32) {
    // fp32 rows of 32 floats = 128B = 8 chunks, XOR-8 swizzle
    const float* Af = (const float*)vp.A;
    const int arow = lane >> 3;   // 0..7
    const int slot8 = lane & 7;
#pragma unroll
    for (int i = 0; i < 4; i++) {
      int r = wave * 32 + i * 8 + arow;
      int c = slot8 ^ (r & 7);
      gAf[i] = Af + (size_t)(m0 + r) * lda + c * 4;
      lAf[i] = (float*)smem + (wave * 32 + i * 8) * 32;
    }
  } else {
    const u16* Ab = (const u16*)vp.A;
    const int rA0 = wave * 32 + srow;
    const int rA1 = rA0 + 16;
    const int cA0 = slot4 ^ ((rA0 >> 1) & 3);
    const int cA1 = slot4 ^ ((rA1 >> 1) & 3);
    gAb0 = Ab + (size_t)(m0 + rA0) * lda + cA0 * 8;
    gAb1 = Ab + (size_t)(m0 + rA1) * lda + cA1 * 8;
    lAb0 = (u16*)smem + (wave * 32) * 32;
    lAb1 = (u16*)smem + (wave * 32 + 16) * 32;
  }

  // ---- fragment offsets (swizzle-aware); wave covers a 64x64 quadrant
  const int lm = lane & 15;
  const int q = lane >> 4;
  const int wm = (wave >> 1) * 64;
  const int wn = (wave & 1) * 64;
  int aoff0[4], aoff1[4], boff[4];
#pragma unroll
  for (int i = 0; i < 4; i++) {
    int ml = wm + i * 16 + lm;
    if constexpr (AF32) {
      aoff0[i] = ml * 32 + ((2 * q) ^ (ml & 7)) * 4;      // float units
      aoff1[i] = ml * 32 + ((2 * q + 1) ^ (ml & 7)) * 4;
    } else {
      aoff0[i] = ml * 32 + (q ^ ((ml >> 1) & 3)) * 8;     // u16 units
    }
    int nl = wn + i * 16 + lm;
    boff[i] = nl * 32 + (q ^ ((nl >> 1) & 3)) * 8;
  }

  f32x4 acc[4][4];
#pragma unroll
  for (int i = 0; i < 4; i++)
#pragma unroll
    for (int j = 0; j < 4; j++) acc[i][j] = 0.0f;

  for (int k0 = 0; k0 < K; k0 += BK) {
    if constexpr (AF32) {
#pragma unroll
      for (int i = 0; i < 4; i++) { gload16(gAf[i], lAf[i]); gAf[i] += BK; }
    } else {
      gload16(gAb0, lAb0); gload16(gAb1, lAb1);
      gAb0 += BK; gAb1 += BK;
    }
    gload16(gB0, lB0); gload16(gB1, lB1);
    gB0 += BK; gB1 += BK;
    __syncthreads();

    bf16x8 af[4], bfr[4];
#pragma unroll
    for (int i = 0; i < 4; i++) {
      if constexpr (AF32) {
        f32x4 lo = *(const f32x4*)((const float*)smem + aoff0[i]);
        f32x4 hi = *(const f32x4*)((const float*)smem + aoff1[i]);
        bf16x8 a;
#pragma unroll
        for (int tt = 0; tt < 4; tt++) { a[tt] = (__bf16)lo[tt]; a[tt + 4] = (__bf16)hi[tt]; }
        af[i] = a;
      } else {
        af[i] = *(const bf16x8*)((const u16*)smem + aoff0[i]);
      }
    }
#pragma unroll
    for (int j = 0; j < 4; j++) bfr[j] = *(const bf16x8*)(Bs + boff[j]);
#pragma unroll
    for (int i = 0; i < 4; i++)
#pragma unroll
      for (int j = 0; j < 4; j++)
        acc[i][j] = __builtin_amdgcn_mfma_f32_16x16x32_bf16(af[i], bfr[j], acc[i][j], 0, 0, 0);
    __syncthreads();
  }

  // ---- epilogue. C/D layout: col = lane&15, row = quad*4 + reg.
#pragma unroll
  for (int j = 0; j < 4; j++) {
    const int n = n0 + wn + j * 16 + lm;
    float bv = 0.0f;
    if (FLAGS & 2) bv = vp.bias[n];
#pragma unroll
    for (int i = 0; i < 4; i++) {
      const int mb = m0 + wm + i * 16 + q * 4;
      float v0 = acc[i][j][0], v1 = acc[i][j][1], v2 = acc[i][j][2], v3 = acc[i][j][3];
      if (FLAGS & 2) { v0 += bv; v1 += bv; v2 += bv; v3 += bv; }
      if (FLAGS & 4) {
        v0 = fmaxf(v0, 0.0f); v1 = fmaxf(v1, 0.0f);
        v2 = fmaxf(v2, 0.0f); v3 = fmaxf(v3, 0.0f);
      }
      if constexpr ((FLAGS & 1) != 0) {
        u16x4 pk;
        pk[0] = f2bf(v0); pk[1] = f2bf(v1); pk[2] = f2bf(v2); pk[3] = f2bf(v3);
        *(u16x4*)((u16*)vp.C + (size_t)n * MTOT + mb) = pk;
      } else if constexpr (CF32) {
        float* cp = (float*)vp.C + (size_t)mb * N + n;
        cp[0] = v0; cp[N] = v1; cp[2 * N] = v2; cp[3 * N] = v3;
      } else {
        u16* cp = (u16*)vp.C + (size_t)mb * N + n;
        cp[0] = f2bf(v0); cp[N] = f2bf(v1); cp[2 * N] = f2bf(v2); cp[3 * N] = f2bf(v3);
      }
    }
  }
}

// fp32 -> bf16 bulk conversion (adj), 8 elems/thread
__global__ __launch_bounds__(256) void cvt_kernel(const float* __restrict__ in,
                                                  u16* __restrict__ out, long n8) {
  long i = (long)blockIdx.x * 256 + threadIdx.x;
  if (i >= n8) return;
  const f32x4* p = (const f32x4*)in + i * 2;
  f32x4 a = p[0], b = p[1];
  u16x8 o;
#pragma unroll
  for (int t = 0; t < 4; t++) { o[t] = f2bf(a[t]); o[t + 4] = f2bf(b[t]); }
  ((u16x8*)out)[i] = o;
}

struct PrepParams {
  const float* W1[5]; u16* W1T[5];
  const float* W2[5]; u16* W2T[5];
  const float* xl; float* xlp;
  int d[5]; int Kp[5];
};

__global__ void prep_kernel(PrepParams p, int total) {
  int idx = blockIdx.x * 256 + threadIdx.x;
  if (idx >= total) return;
  int off = 0;
  // W1T[v]: [256][Kp] bf16 = W1[k][n] (zero-pad k >= d)
#pragma unroll
  for (int v = 0; v < 5; v++) {
    int sz = 256 * p.Kp[v];
    if (idx < off + sz) {
      int r = idx - off;
      int n = r / p.Kp[v];
      int k = r - n * p.Kp[v];
      p.W1T[v][r] = (k < p.d[v]) ? f2bf(p.W1[v][(size_t)k * 256 + n]) : (u16)0;
      return;
    }
    off += sz;
  }
  // W2T[v]: [128][256] bf16 = W2[k][n]
#pragma unroll
  for (int v = 0; v < 5; v++) {
    if (idx < off + 128 * 256) {
      int r = idx - off;
      int n = r >> 8, k = r & 255;
      p.W2T[v][r] = f2bf(p.W2[v][(size_t)k * 128 + n]);
      return;
    }
    off += 128 * 256;
  }
  // x_liwc padded 93 -> 96 (stays fp32)
  {
    int r = idx - off;
    int m = r / 96, k = r - m * 96;
    p.xlp[r] = (k < 93) ? p.xl[(size_t)m * 93 + k] : 0.0f;
  }
}

extern "C" void kernel_launch(void* const* d_in, const int* in_sizes, int n_in,
                              void* d_out, int out_size, void* d_ws, size_t ws_size,
                              hipStream_t stream) {
  (void)in_sizes; (void)n_in; (void)out_size;
  static const int dims[5] = {768, 64, 93, 256, 768};
  static const int Kp[5]   = {768, 64, 96, 256, 768};

  const float *adjf[5], *xf[5], *W1f[5], *b1f[5], *W2f[5], *b2f[5];
  for (int v = 0; v < 5; v++) {
    adjf[v] = (const float*)d_in[6 * v + 0];
    xf[v]   = (const float*)d_in[6 * v + 1];
    W1f[v]  = (const float*)d_in[6 * v + 2];
    b1f[v]  = (const float*)d_in[6 * v + 3];
    W2f[v]  = (const float*)d_in[6 * v + 4];
    b2f[v]  = (const float*)d_in[6 * v + 5];
  }

  char* ws = (char*)d_ws;
  size_t off = 0;
  auto carve = [&](size_t bytes) { char* pp = ws + off; off += (bytes + 15) & ~(size_t)15; return pp; };
  u16* W1T[5]; for (int v = 0; v < 5; v++) W1T[v] = (u16*)carve((size_t)256 * Kp[v] * 2);
  u16* W2T[5]; for (int v = 0; v < 5; v++) W2T[v] = (u16*)carve((size_t)128 * 256 * 2);
  float* xlp = (float*)carve((size_t)4096 * 96 * 4);
  u16* Y1T[5]; for (int v = 0; v < 5; v++) Y1T[v] = (u16*)carve((size_t)256 * 4096 * 2);
  u16* HT[5];  for (int v = 0; v < 5; v++) HT[v]  = (u16*)carve((size_t)256 * 4096 * 2);
  u16* G[5];   for (int v = 0; v < 5; v++) G[v]   = (u16*)carve((size_t)4096 * 256 * 2);
  u16* adjb[5]; for (int v = 0; v < 5; v++) adjb[v] = (u16*)carve((size_t)4096 * 4096 * 2);
  const bool big = ws_size >= off;   // enough scratch for bf16 adj copies

  // prep: weight transposes (fp32 -> bf16) + fp32 liwc padding
  PrepParams pp;
  int prepTot = 0;
  for (int v = 0; v < 5; v++) {
    pp.W1[v] = W1f[v]; pp.W1T[v] = W1T[v];
    pp.W2[v] = W2f[v]; pp.W2T[v] = W2T[v];
    pp.d[v] = dims[v]; pp.Kp[v] = Kp[v];
    prepTot += 256 * Kp[v];
  }
  pp.xl = xf[2]; pp.xlp = xlp;
  prepTot += 5 * 128 * 256 + 4096 * 96;
  prep_kernel<<<(prepTot + 255) / 256, 256, 0, stream>>>(pp, prepTot);

  if (big) {
    const long n8 = (long)4096 * 4096 / 8;  // 2,097,152
    for (int v = 0; v < 5; v++)
      cvt_kernel<<<(int)(n8 / 256), 256, 0, stream>>>(adjf[v], adjb[v], n8);
  }

  // Phase A: Y1T = (x @ W1)^T   (A fp32, transposed bf16 store)
  Params5 pa;
  for (int v = 0; v < 5; v++)
    pa.v[v] = ViewParams{ (v == 2 ? (const void*)xlp : (const void*)xf[v]), W1T[v], Y1T[v],
                          nullptr, Kp[v], Kp[v], 256 };
  gemm_kernel<1, true, false><<<320, 256, 0, stream>>>(pa, 64, 2);

  // Phase B: HT = relu(adj @ Y1 + b1)^T
  Params5 pb;
  for (int v = 0; v < 5; v++)
    pb.v[v] = ViewParams{ big ? (const void*)adjb[v] : (const void*)adjf[v], Y1T[v], HT[v],
                          b1f[v], 4096, 4096, 256 };
  if (big) gemm_kernel<7, false, false><<<320, 256, 0, stream>>>(pb, 64, 2);
  else     gemm_kernel<7, true,  false><<<320, 256, 0, stream>>>(pb, 64, 2);

  // Phase C: G = adj @ H   (row-major bf16 store)
  Params5 pc;
  for (int v = 0; v < 5; v++)
    pc.v[v] = ViewParams{ big ? (const void*)adjb[v] : (const void*)adjf[v], HT[v], G[v],
                          nullptr, 4096, 4096, 256 };
  if (big) gemm_kernel<0, false, false><<<320, 256, 0, stream>>>(pc, 64, 2);
  else     gemm_kernel<0, true,  false><<<320, 256, 0, stream>>>(pc, 64, 2);

  // Phase D: out = G @ W2 + b2   (fp32 store to d_out)
  Params5 pd;
  float* outp = (float*)d_out;
  for (int v = 0; v < 5; v++)
    pd.v[v] = ViewParams{ G[v], W2T[v], outp + (size_t)v * 4096 * 128, b2f[v], 256, 256, 128 };
  gemm_kernel<2, false, true><<<160, 256, 0, stream>>>(pd, 32, 1);
}

// Round 3
// 612.897 us; speedup vs baseline: 1.0570x; 1.0570x over previous
//
#include <hip/hip_runtime.h>
#include <stdint.h>

typedef unsigned short u16;
typedef __attribute__((ext_vector_type(8))) __bf16 bf16x8;
typedef __attribute__((ext_vector_type(4))) float f32x4;
typedef __attribute__((ext_vector_type(4))) u16 u16x4;
typedef __attribute__((ext_vector_type(8))) u16 u16x8;

#define BM 128
#define BN 128
#define BK 32
#define MTOT 4096

__device__ __forceinline__ u16 f2bf(float f) {
  union { float f; uint32_t u; } x; x.f = f;
  uint32_t r = x.u + 0x7FFFu + ((x.u >> 16) & 1u);
  return (u16)(r >> 16);
}
__device__ __forceinline__ float bf2f(u16 h) {
  union { uint32_t u; float f; } x; x.u = ((uint32_t)h) << 16;
  return x.f;
}

__device__ __forceinline__ void gload16(const void* g, void* lds) {
  __builtin_amdgcn_global_load_lds(
      (const __attribute__((address_space(1))) void*)g,
      (__attribute__((address_space(3))) void*)lds, 16, 0, 0);
}

struct ViewParams {
  const void* A;    // [M][lda] row-major; fp32 if AF32 else bf16
  const u16* BT;    // [N][ldab] row-major bf16 (B transposed)
  void* C;          // bf16 unless CF32
  const float* bias;
  int ldab, lda, N;
  int kspan;            // K elements per k-chunk (loop length)
  size_t partStride;    // element stride between k-chunk output buffers
};
struct Params5 { ViewParams v[5]; };

// FLAGS: 1 = transposed bf16 store (C is [N][4096]), 2 = +bias, 4 = relu
template <int FLAGS, bool AF32, bool CF32>
__global__ __launch_bounds__(256) void gemm_kernel(Params5 p, int tilesPerView,
                                                   int ntiles, int kchunks) {
  constexpr int ABYTES = AF32 ? (BM * BK * 4) : (BM * BK * 2);
  __shared__ __align__(16) char smem[ABYTES + BN * BK * 2];
  u16* Bs = (u16*)(smem + ABYTES);

  const int bid = blockIdx.x;
  const int view = bid / tilesPerView;
  const int t = bid - view * tilesPerView;
  const int kc = t % kchunks;
  const int t2 = t / kchunks;
  const int nt = t2 % ntiles;
  const int mt = t2 / ntiles;
  ViewParams vp = p.v[view];
  const int ldab = vp.ldab, lda = vp.lda, N = vp.N;
  const int m0 = mt * BM, n0 = nt * BN;
  const int kbase = kc * vp.kspan;

  const int tid = threadIdx.x;
  const int wave = tid >> 6;
  const int lane = tid & 63;

  // ---- B staging (bf16): rows of 32 u16 = 64B = 4 chunks, XOR-4 swizzle
  const int srow = lane >> 2;
  const int slot4 = lane & 3;
  const int rB0 = wave * 32 + srow;
  const int rB1 = rB0 + 16;
  const int cB0 = slot4 ^ ((rB0 >> 1) & 3);
  const int cB1 = slot4 ^ ((rB1 >> 1) & 3);
  const u16* gB0 = vp.BT + (size_t)(n0 + rB0) * ldab + kbase + cB0 * 8;
  const u16* gB1 = vp.BT + (size_t)(n0 + rB1) * ldab + kbase + cB1 * 8;
  u16* lB0 = Bs + (wave * 32) * 32;
  u16* lB1 = Bs + (wave * 32 + 16) * 32;

  // ---- A staging
  const float* gAf[4];
  float* lAf[4];
  const u16 *gAb0 = nullptr, *gAb1 = nullptr;
  u16 *lAb0 = nullptr, *lAb1 = nullptr;
  if constexpr (AF32) {
    const float* Af = (const float*)vp.A;
    const int arow = lane >> 3;
    const int slot8 = lane & 7;
#pragma unroll
    for (int i = 0; i < 4; i++) {
      int r = wave * 32 + i * 8 + arow;
      int c = slot8 ^ (r & 7);
      gAf[i] = Af + (size_t)(m0 + r) * lda + kbase + c * 4;
      lAf[i] = (float*)smem + (wave * 32 + i * 8) * 32;
    }
  } else {
    const u16* Ab = (const u16*)vp.A;
    const int rA0 = wave * 32 + srow;
    const int rA1 = rA0 + 16;
    const int cA0 = slot4 ^ ((rA0 >> 1) & 3);
    const int cA1 = slot4 ^ ((rA1 >> 1) & 3);
    gAb0 = Ab + (size_t)(m0 + rA0) * lda + kbase + cA0 * 8;
    gAb1 = Ab + (size_t)(m0 + rA1) * lda + kbase + cA1 * 8;
    lAb0 = (u16*)smem + (wave * 32) * 32;
    lAb1 = (u16*)smem + (wave * 32 + 16) * 32;
  }

  // ---- fragment offsets (swizzle-aware); wave covers a 64x64 quadrant
  const int lm = lane & 15;
  const int q = lane >> 4;
  const int wm = (wave >> 1) * 64;
  const int wn = (wave & 1) * 64;
  int aoff0[4], aoff1[4], boff[4];
#pragma unroll
  for (int i = 0; i < 4; i++) {
    int ml = wm + i * 16 + lm;
    if constexpr (AF32) {
      aoff0[i] = ml * 32 + ((2 * q) ^ (ml & 7)) * 4;
      aoff1[i] = ml * 32 + ((2 * q + 1) ^ (ml & 7)) * 4;
    } else {
      aoff0[i] = ml * 32 + (q ^ ((ml >> 1) & 3)) * 8;
    }
    int nl = wn + i * 16 + lm;
    boff[i] = nl * 32 + (q ^ ((nl >> 1) & 3)) * 8;
  }

  f32x4 acc[4][4];
#pragma unroll
  for (int i = 0; i < 4; i++)
#pragma unroll
    for (int j = 0; j < 4; j++) acc[i][j] = 0.0f;

  for (int ks = 0; ks < vp.kspan; ks += BK) {
    if constexpr (AF32) {
#pragma unroll
      for (int i = 0; i < 4; i++) { gload16(gAf[i], lAf[i]); gAf[i] += BK; }
    } else {
      gload16(gAb0, lAb0); gload16(gAb1, lAb1);
      gAb0 += BK; gAb1 += BK;
    }
    gload16(gB0, lB0); gload16(gB1, lB1);
    gB0 += BK; gB1 += BK;
    __syncthreads();

    bf16x8 af[4], bfr[4];
#pragma unroll
    for (int i = 0; i < 4; i++) {
      if constexpr (AF32) {
        f32x4 lo = *(const f32x4*)((const float*)smem + aoff0[i]);
        f32x4 hi = *(const f32x4*)((const float*)smem + aoff1[i]);
        bf16x8 a;
#pragma unroll
        for (int tt = 0; tt < 4; tt++) { a[tt] = (__bf16)lo[tt]; a[tt + 4] = (__bf16)hi[tt]; }
        af[i] = a;
      } else {
        af[i] = *(const bf16x8*)((const u16*)smem + aoff0[i]);
      }
    }
#pragma unroll
    for (int j = 0; j < 4; j++) bfr[j] = *(const bf16x8*)(Bs + boff[j]);
#pragma unroll
    for (int i = 0; i < 4; i++)
#pragma unroll
      for (int j = 0; j < 4; j++)
        acc[i][j] = __builtin_amdgcn_mfma_f32_16x16x32_bf16(af[i], bfr[j], acc[i][j], 0, 0, 0);
    __syncthreads();
  }

  // ---- epilogue. C/D layout: col = lane&15, row = quad*4 + reg.
#pragma unroll
  for (int j = 0; j < 4; j++) {
    const int n = n0 + wn + j * 16 + lm;
    float bv = 0.0f;
    if (FLAGS & 2) bv = vp.bias[n];
#pragma unroll
    for (int i = 0; i < 4; i++) {
      const int mb = m0 + wm + i * 16 + q * 4;
      float v0 = acc[i][j][0], v1 = acc[i][j][1], v2 = acc[i][j][2], v3 = acc[i][j][3];
      if (FLAGS & 2) { v0 += bv; v1 += bv; v2 += bv; v3 += bv; }
      if (FLAGS & 4) {
        v0 = fmaxf(v0, 0.0f); v1 = fmaxf(v1, 0.0f);
        v2 = fmaxf(v2, 0.0f); v3 = fmaxf(v3, 0.0f);
      }
      if constexpr ((FLAGS & 1) != 0) {
        u16x4 pk;
        pk[0] = f2bf(v0); pk[1] = f2bf(v1); pk[2] = f2bf(v2); pk[3] = f2bf(v3);
        *(u16x4*)((u16*)vp.C + (size_t)kc * vp.partStride + (size_t)n * MTOT + mb) = pk;
      } else if constexpr (CF32) {
        float* cp = (float*)vp.C + (size_t)mb * N + n;
        cp[0] = v0; cp[N] = v1; cp[2 * N] = v2; cp[3 * N] = v3;
      } else {
        u16* cp = (u16*)vp.C + (size_t)kc * vp.partStride + (size_t)mb * N + n;
        cp[0] = f2bf(v0); cp[N] = f2bf(v1); cp[2 * N] = f2bf(v2); cp[3 * N] = f2bf(v3);
      }
    }
  }
}

// merged fp32 -> bf16 adj conversion, all 5 views, 8 elems/thread
struct CvtParams { const float* src[5]; u16* dst; };
__global__ __launch_bounds__(256) void cvt_kernel(CvtParams cp) {
  long i = (long)blockIdx.x * 256 + threadIdx.x;   // 5 * 2^21 threads exactly
  int v = (int)(i >> 21);
  long r = i & ((1L << 21) - 1);
  const f32x4* p = (const f32x4*)cp.src[v] + r * 2;
  f32x4 a = p[0], b = p[1];
  u16x8 o;
#pragma unroll
  for (int t = 0; t < 4; t++) { o[t] = f2bf(a[t]); o[t + 4] = f2bf(b[t]); }
  ((u16x8*)cp.dst)[i] = o;
}

// combine k-chunk partials: out[v] = (relu?)(sum_kc parts[kc][v] + bias)
struct CombParams { const u16* parts; u16* out; const float* b[5]; int kchunks; };
template <bool RELU>
__global__ __launch_bounds__(256) void comb_kernel(CombParams cp) {
  int idx = blockIdx.x * 256 + threadIdx.x;   // 5 * 2^17 threads exactly
  int v = idx >> 17;
  int e = (idx & 131071) << 3;
  float acc[8] = {0, 0, 0, 0, 0, 0, 0, 0};
  for (int kc = 0; kc < cp.kchunks; kc++) {
    u16x8 t = *(const u16x8*)(cp.parts + (((size_t)(kc * 5 + v)) << 20) + e);
#pragma unroll
    for (int j = 0; j < 8; j++) acc[j] += bf2f(t[j]);
  }
  if (RELU) {
    float bv = cp.b[v][e >> 12];
#pragma unroll
    for (int j = 0; j < 8; j++) acc[j] = fmaxf(acc[j] + bv, 0.0f);
  }
  u16x8 o;
#pragma unroll
  for (int j = 0; j < 8; j++) o[j] = f2bf(acc[j]);
  *(u16x8*)(cp.out + (((size_t)v) << 20) + e) = o;
}

struct PrepParams {
  const float* W1[5]; u16* W1T[5];
  const float* W2[5]; u16* W2T[5];
  const float* xl; float* xlp;
  int d[5]; int Kp[5];
};

__global__ void prep_kernel(PrepParams p, int total) {
  int idx = blockIdx.x * 256 + threadIdx.x;
  if (idx >= total) return;
  int off = 0;
#pragma unroll
  for (int v = 0; v < 5; v++) {
    int sz = 256 * p.Kp[v];
    if (idx < off + sz) {
      int r = idx - off;
      int n = r / p.Kp[v];
      int k = r - n * p.Kp[v];
      p.W1T[v][r] = (k < p.d[v]) ? f2bf(p.W1[v][(size_t)k * 256 + n]) : (u16)0;
      return;
    }
    off += sz;
  }
#pragma unroll
  for (int v = 0; v < 5; v++) {
    if (idx < off + 128 * 256) {
      int r = idx - off;
      int n = r >> 8, k = r & 255;
      p.W2T[v][r] = f2bf(p.W2[v][(size_t)k * 128 + n]);
      return;
    }
    off += 128 * 256;
  }
  {
    int r = idx - off;
    int m = r / 96, k = r - m * 96;
    p.xlp[r] = (k < 93) ? p.xl[(size_t)m * 93 + k] : 0.0f;
  }
}

extern "C" void kernel_launch(void* const* d_in, const int* in_sizes, int n_in,
                              void* d_out, int out_size, void* d_ws, size_t ws_size,
                              hipStream_t stream) {
  (void)in_sizes; (void)n_in; (void)out_size;
  static const int dims[5] = {768, 64, 93, 256, 768};
  static const int Kp[5]   = {768, 64, 96, 256, 768};

  const float *adjf[5], *xf[5], *W1f[5], *b1f[5], *W2f[5], *b2f[5];
  for (int v = 0; v < 5; v++) {
    adjf[v] = (const float*)d_in[6 * v + 0];
    xf[v]   = (const float*)d_in[6 * v + 1];
    W1f[v]  = (const float*)d_in[6 * v + 2];
    b1f[v]  = (const float*)d_in[6 * v + 3];
    W2f[v]  = (const float*)d_in[6 * v + 4];
    b2f[v]  = (const float*)d_in[6 * v + 5];
  }

  const size_t VIEW = (size_t)256 * 4096;   // 1,048,576 elements
  char* ws = (char*)d_ws;
  size_t off = 0;
  auto carve = [&](size_t bytes) { char* pp = ws + off; off += (bytes + 15) & ~(size_t)15; return pp; };
  u16* W1T[5]; for (int v = 0; v < 5; v++) W1T[v] = (u16*)carve((size_t)256 * Kp[v] * 2);
  u16* W2T[5]; for (int v = 0; v < 5; v++) W2T[v] = (u16*)carve((size_t)128 * 256 * 2);
  float* xlp = (float*)carve((size_t)4096 * 96 * 4);
  u16* Y1T = (u16*)carve(5 * VIEW * 2);      // later reused as combined G
  u16* PARTS = (u16*)carve(2 * 5 * VIEW * 2); // k-chunk partials (B), reused (C)
  u16* HT = (u16*)carve(5 * VIEW * 2);       // combined relu(adj@Y1+b1)^T
  u16* adjb = (u16*)carve((size_t)5 * 4096 * 4096 * 2);
  const bool ksplit = ws_size >= off;
  u16* G = Y1T;   // alias: Y1T dead before G is written

  // prep: weight transposes (fp32 -> bf16) + fp32 liwc padding
  PrepParams pp;
  int prepTot = 0;
  for (int v = 0; v < 5; v++) {
    pp.W1[v] = W1f[v]; pp.W1T[v] = W1T[v];
    pp.W2[v] = W2f[v]; pp.W2T[v] = W2T[v];
    pp.d[v] = dims[v]; pp.Kp[v] = Kp[v];
    prepTot += 256 * Kp[v];
  }
  pp.xl = xf[2]; pp.xlp = xlp;
  prepTot += 5 * 128 * 256 + 4096 * 96;
  prep_kernel<<<(prepTot + 255) / 256, 256, 0, stream>>>(pp, prepTot);

  // Phase A: Y1T = (x @ W1)^T   (A fp32, transposed bf16 store)
  Params5 pa;
  for (int v = 0; v < 5; v++)
    pa.v[v] = ViewParams{ (v == 2 ? (const void*)xlp : (const void*)xf[v]), W1T[v], Y1T + v * VIEW,
                          nullptr, Kp[v], Kp[v], 256, Kp[v], 0 };
  gemm_kernel<1, true, false><<<320, 256, 0, stream>>>(pa, 64, 2, 1);

  // adj fp32 -> bf16 (single merged launch; adjb lands L3-warm for phase B)
  CvtParams cv;
  for (int v = 0; v < 5; v++) cv.src[v] = adjf[v];
  cv.dst = adjb;
  cvt_kernel<<<40960, 256, 0, stream>>>(cv);

  if (ksplit) {
    // Phase B: PARTS[kc][v] = (adj @ Y1)^T partials, K split in 2
    Params5 pb;
    for (int v = 0; v < 5; v++)
      pb.v[v] = ViewParams{ adjb + (size_t)v * 4096 * 4096, Y1T + v * VIEW, PARTS + v * VIEW,
                            nullptr, 4096, 4096, 256, 2048, 5 * VIEW };
    gemm_kernel<1, false, false><<<640, 256, 0, stream>>>(pb, 128, 2, 2);

    // combine1: HT = relu(sum parts + b1)
    CombParams c1{ PARTS, HT, { b1f[0], b1f[1], b1f[2], b1f[3], b1f[4] }, 2 };
    comb_kernel<true><<<2560, 256, 0, stream>>>(c1);

    // Phase C: PARTS[kc][v] = (adj @ H) partials (row-major), K split in 2
    Params5 pc;
    for (int v = 0; v < 5; v++)
      pc.v[v] = ViewParams{ adjb + (size_t)v * 4096 * 4096, HT + v * VIEW, PARTS + v * VIEW,
                            nullptr, 4096, 4096, 256, 2048, 5 * VIEW };
    gemm_kernel<0, false, false><<<640, 256, 0, stream>>>(pc, 128, 2, 2);

    // combine2: G = sum parts
    CombParams c2{ PARTS, G, { nullptr, nullptr, nullptr, nullptr, nullptr }, 2 };
    comb_kernel<false><<<2560, 256, 0, stream>>>(c2);
  } else {
    // fallback: proven round-2 structure (no K-split)
    Params5 pb;
    for (int v = 0; v < 5; v++)
      pb.v[v] = ViewParams{ adjb + (size_t)v * 4096 * 4096, Y1T + v * VIEW, HT + v * VIEW,
                            b1f[v], 4096, 4096, 256, 4096, 0 };
    gemm_kernel<7, false, false><<<320, 256, 0, stream>>>(pb, 64, 2, 1);
    Params5 pc;
    for (int v = 0; v < 5; v++)
      pc.v[v] = ViewParams{ adjb + (size_t)v * 4096 * 4096, HT + v * VIEW, G + v * VIEW,
                            nullptr, 4096, 4096, 256, 4096, 0 };
    gemm_kernel<0, false, false><<<320, 256, 0, stream>>>(pc, 64, 2, 1);
  }

  // Phase D: out = G @ W2 + b2   (fp32 store to d_out)
  Params5 pd;
  float* outp = (float*)d_out;
  for (int v = 0; v < 5; v++)
    pd.v[v] = ViewParams{ G + v * VIEW, W2T[v], outp + (size_t)v * 4096 * 128, b2f[v],
                          256, 256, 128, 256, 0 };
  gemm_kernel<2, false, true><<<160, 256, 0, stream>>>(pd, 32, 1, 1);
}